// Round 3
// baseline (556.658 us; speedup 1.0000x reference)
//
#include <hip/hip_runtime.h>
#include <hip/hip_bf16.h>
#include <cstdint>
#include <cstddef>

// out[8192,4096] = x @ W^T + bias + 2*((x@A^T)@B^T)
// Fold: W' = W + 2*B@A (rank-16), then ONE bf16 MFMA GEMM: out = x @ W'^T + bias.
// R5: R4 structure (fused A-cast in GEMM, no separate x-cast pass) with the
//     A-path loads made PLAIN f32x4 loads (compiler-modeled, auto-waitcnt,
//     no backedge-copy hazard) instead of inline-asm global_load_dwordx4.
//     B (folded bf16 W') stays global_load_lds with counted vmcnt.
//     Ring-4 LDS, raw barriers, swizzled chunks, setprio around MFMA.

#define IN_F   4096
#define OUT_F  4096
#define MROWS  8192   // 4*2048
#define RLORA  16
#define LORA_SCALE 2.0f

// GEMM geometry
#define BM   256
#define BN   256
#define BKT  32               // K per pipeline sub-tile
#define NT   (IN_F / BKT)     // 128 phases

typedef __bf16 bf16x8 __attribute__((ext_vector_type(8)));
typedef float  f32x4  __attribute__((ext_vector_type(4)));
typedef int    i32x4  __attribute__((ext_vector_type(4)));

__device__ __forceinline__ unsigned short f2bf_rne(float f) {
    union { float f; unsigned u; } v; v.f = f;
    unsigned u = v.u;
    return (unsigned short)((u + 0x7FFFu + ((u >> 16) & 1u)) >> 16);
}

__device__ __forceinline__ void gl_lds16(const unsigned short* g, unsigned short* l) {
    __builtin_amdgcn_global_load_lds(
        (const __attribute__((address_space(1))) unsigned int*)g,
        (__attribute__((address_space(3))) unsigned int*)l,
        16, 0, 0);
}

__device__ __forceinline__ int cvtpk(float lo, float hi) {
    int r;
    asm volatile("v_cvt_pk_bf16_f32 %0, %1, %2" : "=v"(r) : "v"(lo), "v"(hi));
    return r;
}

// ---- fold: W' = bf16(W + 2*B@A), one block per output row ------------------

__global__ void fold_w(const float* __restrict__ W,
                       const float* __restrict__ A,
                       const float* __restrict__ B,
                       unsigned short* __restrict__ wb) {
    __shared__ float sB[RLORA];
    const int o = blockIdx.x;                     // output row
    if (threadIdx.x < RLORA) sB[threadIdx.x] = B[o * RLORA + threadIdx.x];
    __syncthreads();
    const float4* W4  = (const float4*)(W + (size_t)o * IN_F);
    ushort4*      Wp4 = (ushort4*)(wb + (size_t)o * IN_F);
    for (int i4 = threadIdx.x; i4 < IN_F / 4; i4 += blockDim.x) {
        float4 w = W4[i4];
        float ax = 0.f, ay = 0.f, az = 0.f, aw = 0.f;
        #pragma unroll
        for (int r = 0; r < RLORA; ++r) {
            float4 a = ((const float4*)(A + (size_t)r * IN_F))[i4];
            float s = sB[r];
            ax += s * a.x; ay += s * a.y; az += s * a.z; aw += s * a.w;
        }
        w.x += LORA_SCALE * ax; w.y += LORA_SCALE * ay;
        w.z += LORA_SCALE * az; w.w += LORA_SCALE * aw;
        ushort4 ov;
        ov.x = f2bf_rne(w.x); ov.y = f2bf_rne(w.y);
        ov.z = f2bf_rne(w.z); ov.w = f2bf_rne(w.w);
        Wp4[i4] = ov;
    }
}

// ---- GEMM: C[M,N] = f32(X) @ Wb^T + bias  (ring-4, fused A-cast) -----------
//
// LDS chunk swizzle (chunk = 16 B = 8 bf16): LDS chunk q of a tile holds
// global chunk (row=q>>2, kc=(q&3)^((row>>1)&3)).
//   - B: global_load_lds writes linear chunks; source address pre-swizzled.
//   - A: reg-staged; thread loads 2 chunks (8 f32 each, PLAIN loads),
//        cvt_pk to bf16, writes 16B to chunk slots q0,q1 directly.
// Residency invariants (order-insensitive within an iteration):
//   - A-reg readiness: compiler-inserted waitcnt before the cvt uses.
//   - B(p+1) in LDS at end of phase p: vmcnt(6) retires everything older
//     than the 6 VMEM ops issued this iteration (in-order retirement).
//   - A(p+1) ds_writes visible: lgkmcnt(0) before s_barrier.
// vmcnt never drains to 0 in the main loop.

__device__ __forceinline__ void mfma_phase(unsigned bufb, unsigned aoff, unsigned boff,
                                           f32x4 (&acc)[8][4]) {
    const unsigned ab = bufb + aoff;
    const unsigned bb = bufb + boff;
    i32x4 aR[8]; i32x4 bR[4];
    asm volatile("ds_read_b128 %0, %1"             : "=v"(bR[0]) : "v"(bb));
    asm volatile("ds_read_b128 %0, %1 offset:1024" : "=v"(bR[1]) : "v"(bb));
    asm volatile("ds_read_b128 %0, %1 offset:2048" : "=v"(bR[2]) : "v"(bb));
    asm volatile("ds_read_b128 %0, %1 offset:3072" : "=v"(bR[3]) : "v"(bb));
    asm volatile("ds_read_b128 %0, %1"             : "=v"(aR[0]) : "v"(ab));
    asm volatile("ds_read_b128 %0, %1 offset:1024" : "=v"(aR[1]) : "v"(ab));
    asm volatile("ds_read_b128 %0, %1 offset:2048" : "=v"(aR[2]) : "v"(ab));
    asm volatile("ds_read_b128 %0, %1 offset:3072" : "=v"(aR[3]) : "v"(ab));
    asm volatile("ds_read_b128 %0, %1 offset:4096" : "=v"(aR[4]) : "v"(ab));
    asm volatile("ds_read_b128 %0, %1 offset:5120" : "=v"(aR[5]) : "v"(ab));
    asm volatile("ds_read_b128 %0, %1 offset:6144" : "=v"(aR[6]) : "v"(ab));
    asm volatile("ds_read_b128 %0, %1 offset:7168" : "=v"(aR[7]) : "v"(ab));

    // DS retires in order: any prior ds_writes + first 8 reads retire first.
    asm volatile("s_waitcnt lgkmcnt(4)" ::: "memory");
    __builtin_amdgcn_sched_barrier(0);
    __builtin_amdgcn_s_setprio(1);
    #pragma unroll
    for (int mi = 0; mi < 4; ++mi) {
        const bf16x8 a = __builtin_bit_cast(bf16x8, aR[mi]);
        #pragma unroll
        for (int nj = 0; nj < 4; ++nj)
            acc[mi][nj] = __builtin_amdgcn_mfma_f32_16x16x32_bf16(
                a, __builtin_bit_cast(bf16x8, bR[nj]), acc[mi][nj], 0, 0, 0);
    }
    asm volatile("s_waitcnt lgkmcnt(0)" ::: "memory");
    __builtin_amdgcn_sched_barrier(0);
    #pragma unroll
    for (int mi = 4; mi < 8; ++mi) {
        const bf16x8 a = __builtin_bit_cast(bf16x8, aR[mi]);
        #pragma unroll
        for (int nj = 0; nj < 4; ++nj)
            acc[mi][nj] = __builtin_amdgcn_mfma_f32_16x16x32_bf16(
                a, __builtin_bit_cast(bf16x8, bR[nj]), acc[mi][nj], 0, 0, 0);
    }
    __builtin_amdgcn_sched_barrier(0);
    __builtin_amdgcn_s_setprio(0);
}

__global__ __launch_bounds__(512, 2)
void gemm_bt_bias(const float* __restrict__ X,
                  const unsigned short* __restrict__ Wb,
                  const float* __restrict__ bias,
                  float* __restrict__ out) {
    __shared__ __align__(16) unsigned short smem[4 * 16384];  // 4 bufs x (A 16KB + B 16KB)

    const int tid  = threadIdx.x;
    const int wave = tid >> 6;      // 0..7
    const int lane = tid & 63;
    const int quad = lane >> 4;     // 0..3
    const int r16  = lane & 15;
    const int wm   = wave >> 2;     // 0..1 (M half)
    const int wn   = wave & 3;      // 0..3 (N quarter)

    // XCD swizzle: XCD c owns N-tiles {2c,2c+1}; W panel 4 MB = its whole L2.
    const int bid = blockIdx.x;
    const int xcd = bid & 7;
    const int t   = bid >> 3;                    // 0..63
    const int n0  = (xcd * 2 + (t & 1)) * BN;
    const int m0  = (t >> 1) * BM;

    // staging geometry: thread owns LDS chunks q0, q1 of each tile
    const int q0  = wave * 128 + lane;
    const int q1  = q0 + 64;
    const int r0  = q0 >> 2, k0c = (q0 & 3) ^ ((r0 >> 1) & 3);
    const int r1  = q1 >> 2, k1c = (q1 & 3) ^ ((r1 >> 1) & 3);

    const float*          gA0 = X  + (size_t)(m0 + r0) * IN_F + k0c * 8;
    const float*          gA1 = X  + (size_t)(m0 + r1) * IN_F + k1c * 8;
    const unsigned short* gB0 = Wb + (size_t)(n0 + r0) * IN_F + k0c * 8;
    const unsigned short* gB1 = Wb + (size_t)(n0 + r1) * IN_F + k1c * 8;

    const unsigned dB0 = 8192 + wave * 1024;        // B gl_lds dest (ushort units)
    const unsigned dB1 = dB0 + 512;
    const unsigned wA0 = (unsigned)(wave * 1024 + lane * 8);  // A write chunk0
    const unsigned wA1 = wA0 + 512;                           // A write chunk1

    // fragment read addresses (bytes, swizzled)
    const unsigned slot  = (unsigned)(quad ^ ((r16 >> 1) & 3));
    const unsigned aoff  = (unsigned)((wm * 128 + r16) * 64) + slot * 16;
    const unsigned boff  = 16384u + (unsigned)((wn * 64 + r16) * 64) + slot * 16;
    const unsigned sbase = (unsigned)(size_t)
        ((__attribute__((address_space(3))) unsigned short*)smem);

    f32x4 acc[8][4] = {};
    f32x4 s0, s1, s2, s3;                            // A staging regs (1 tile)

#define STAGE_ISSUE(TILE) {                                              \
    unsigned short* Lb = smem + (((TILE) & 3) << 14);                    \
    s0 = ((const f32x4*)gA0)[0]; s1 = ((const f32x4*)gA0)[1];            \
    s2 = ((const f32x4*)gA1)[0]; s3 = ((const f32x4*)gA1)[1];            \
    gA0 += BKT; gA1 += BKT;                                              \
    gl_lds16(gB0, Lb + dB0); gl_lds16(gB1, Lb + dB1);                    \
    gB0 += BKT; gB1 += BKT; }

#define CVT_WR(TILE) {                                                   \
    unsigned short* Bp = smem + (((TILE) & 3) << 14);                    \
    i32x4 w0, w1;                                                        \
    w0[0] = cvtpk(s0[0], s0[1]);  w0[1] = cvtpk(s0[2], s0[3]);           \
    w0[2] = cvtpk(s1[0], s1[1]);  w0[3] = cvtpk(s1[2], s1[3]);           \
    w1[0] = cvtpk(s2[0], s2[1]);  w1[1] = cvtpk(s2[2], s2[3]);           \
    w1[2] = cvtpk(s3[0], s3[1]);  w1[3] = cvtpk(s3[2], s3[3]);           \
    *(i32x4*)(Bp + wA0) = w0;                                            \
    *(i32x4*)(Bp + wA1) = w1; }

    // ---- prologue: tile 0 fully staged; tile 1 issued ----------------------
    STAGE_ISSUE(0)
    asm volatile("s_waitcnt vmcnt(2)" ::: "memory");
    __builtin_amdgcn_sched_barrier(0);
    CVT_WR(0)
    STAGE_ISSUE(1)
    asm volatile("s_waitcnt vmcnt(6)" ::: "memory");   // B(t0) resident
    asm volatile("s_waitcnt lgkmcnt(0)" ::: "memory"); // A(t0) writes visible
    __builtin_amdgcn_s_barrier();

    // ---- main loop ----------------------------------------------------------
    for (int p = 0; p < NT - 2; ++p) {
        asm volatile("s_waitcnt vmcnt(2)" ::: "memory");
        __builtin_amdgcn_sched_barrier(0);
        CVT_WR(p + 1)                                  // compiler waits A(p+1)
        STAGE_ISSUE(p + 2)
        __builtin_amdgcn_sched_barrier(0);
        mfma_phase(sbase + ((unsigned)(p & 3) << 15), aoff, boff, acc);
        asm volatile("s_waitcnt vmcnt(6)" ::: "memory");   // B(p+1) resident
        asm volatile("s_waitcnt lgkmcnt(0)" ::: "memory"); // A(p+1) writes visible
        __builtin_amdgcn_s_barrier();
    }
    // ---- tail: p = NT-2 (cvt last tile, no new issue) ----------------------
    asm volatile("s_waitcnt vmcnt(2)" ::: "memory");
    __builtin_amdgcn_sched_barrier(0);
    CVT_WR(NT - 1)
    __builtin_amdgcn_sched_barrier(0);
    mfma_phase(sbase + ((unsigned)((NT - 2) & 3) << 15), aoff, boff, acc);
    asm volatile("s_waitcnt vmcnt(0)" ::: "memory");
    asm volatile("s_waitcnt lgkmcnt(0)" ::: "memory");
    __builtin_amdgcn_s_barrier();
    // ---- tail: p = NT-1 ----------------------------------------------------
    mfma_phase(sbase + ((unsigned)((NT - 1) & 3) << 15), aoff, boff, acc);

#undef STAGE_ISSUE
#undef CVT_WR

    // ---- epilogue: C = acc + bias ------------------------------------------
    float bv[4];
    #pragma unroll
    for (int nj = 0; nj < 4; ++nj)
        bv[nj] = bias[n0 + wn * 64 + nj * 16 + r16];

    #pragma unroll
    for (int mi = 0; mi < 8; ++mi) {
        #pragma unroll
        for (int i = 0; i < 4; ++i) {
            const int mg = m0 + wm * 128 + mi * 16 + quad * 4 + i;
            float* orow = out + (size_t)mg * OUT_F + (n0 + wn * 64 + r16);
            #pragma unroll
            for (int nj = 0; nj < 4; ++nj)
                orow[nj * 16] = acc[mi][nj][i] + bv[nj];
        }
    }
}

// ---- launch ----------------------------------------------------------------

extern "C" void kernel_launch(void* const* d_in, const int* in_sizes, int n_in,
                              void* d_out, int out_size, void* d_ws, size_t ws_size,
                              hipStream_t stream) {
    const float* x    = (const float*)d_in[0];
    const float* W    = (const float*)d_in[1];
    const float* bias = (const float*)d_in[2];
    const float* A    = (const float*)d_in[3];
    const float* B    = (const float*)d_in[4];
    float* out = (float*)d_out;

    unsigned short* wb = (unsigned short*)d_ws;              // 32 MB bf16 W'

    fold_w<<<OUT_F, 256, 0, stream>>>(W, A, B, wb);
    gemm_bt_bias<<<(MROWS / BM) * (OUT_F / BN), 512, 0, stream>>>(x, wb, bias, out);
}